// Round 4
// baseline (317.981 us; speedup 1.0000x reference)
//
#include <hip/hip_runtime.h>
#include <hip/hip_bf16.h>
#include <cmath>

typedef __bf16 bf16;
typedef __bf16 bf16x4 __attribute__((ext_vector_type(4)));
typedef __bf16 bf16x8 __attribute__((ext_vector_type(8)));
typedef float f32x4 __attribute__((ext_vector_type(4)));

#define BB 2
#define SS 2048
#define DD 1024
#define HH 16
#define WW 16
#define HDD 64
#define DFFD 4096
#define NTOK (BB*SS)

// gelu(x) = x * sigmoid(2*sqrt(2/pi)*(x+0.044715x^3))  == tanh-approx gelu
__device__ __forceinline__ float gelu_f(float x) {
    const float k = 1.5957691216057308f;  // 2*sqrt(2/pi)
    float u = k * (x + 0.044715f * x * x * x);
    return x / (1.0f + __expf(-u));
}

// ---- async global->LDS 16B/lane. LDS dest = wave-uniform base; HW adds lane*16. ----
__device__ __forceinline__ void glds16(const bf16* g, const bf16* l) {
    __builtin_amdgcn_global_load_lds(
        (const __attribute__((address_space(1))) void*)(uintptr_t)(const void*)g,
        (__attribute__((address_space(3))) void*)(unsigned)(uintptr_t)(const void*)l,
        16, 0, 0);
}

// ---------------- fp32 -> bf16 convert, 8 elems/thread ----------------
__global__ __launch_bounds__(256) void conv_kernel(
    const float* __restrict__ src, bf16* __restrict__ dst, int n8)
{
    int i = blockIdx.x * 256 + threadIdx.x;
    if (i >= n8) return;
    f32x4 a = *(const f32x4*)(src + (size_t)i * 8);
    f32x4 b = *(const f32x4*)(src + (size_t)i * 8 + 4);
    bf16x8 v;
#pragma unroll
    for (int j = 0; j < 4; j++) { v[j] = (bf16)a[j]; v[4 + j] = (bf16)b[j]; }
    *(bf16x8*)(dst + (size_t)i * 8) = v;
}

// ---------------- fused LayerNorm: fp32 row -> bf16 row, one block/row ----------------
__global__ __launch_bounds__(256) void ln_kernel(
    const float* __restrict__ x, const float* __restrict__ g, const float* __restrict__ b,
    bf16* __restrict__ out)
{
    const int row = blockIdx.x, t = threadIdx.x;
    f32x4 v = *(const f32x4*)(x + (size_t)row * DD + t * 4);
    float s  = v[0] + v[1] + v[2] + v[3];
    float s2 = v[0]*v[0] + v[1]*v[1] + v[2]*v[2] + v[3]*v[3];
#pragma unroll
    for (int off = 32; off >= 1; off >>= 1) {
        s  += __shfl_xor(s,  off, 64);
        s2 += __shfl_xor(s2, off, 64);
    }
    __shared__ float red[8];
    const int wave = t >> 6;
    if ((t & 63) == 0) { red[wave] = s; red[4 + wave] = s2; }
    __syncthreads();
    float ts  = red[0] + red[1] + red[2] + red[3];
    float ts2 = red[4] + red[5] + red[6] + red[7];
    float mean = ts * (1.0f / DD);
    float var  = ts2 * (1.0f / DD) - mean * mean;
    float rstd = rsqrtf(var + 1e-5f);
    f32x4 gv = *(const f32x4*)(g + t * 4);
    f32x4 bv = *(const f32x4*)(b + t * 4);
    bf16x4 o;
#pragma unroll
    for (int i = 0; i < 4; i++) o[i] = (bf16)((v[i] - mean) * rstd * gv[i] + bv[i]);
    *(bf16x4*)(out + (size_t)row * DD + t * 4) = o;
}

// ======== 256x256 8-wave phase-pipelined GEMM (T1+T2+T3+T4+T5), BK=32 ring-4 ========
// C[M,N] = A[M,K] @ W[N,K]^T + bias.  512 threads = 8 waves (2M x 4N), wave tile 128x64.
// LDS: ring of 4 K-tile slots (A 256x32 + B 256x32 = 32 KB each) = 128 KiB.
// Schedule: iter t computes tile t from ring[t&3], stages tile t+3 (A in phase 0,
// B in phase 1, 2 glds16/thread each). vmcnt(8) before the phase-0 barrier: exactly
// 8 loads (tiles t+1,t+2) were issued after tile t's stage, so vmcnt(8)+barrier
// proves tile t landed for ALL waves (per-wave counters + lockstep). Tail drains
// 8->4->0. Raw s_barrier only (no __syncthreads: would re-insert the vmcnt(0) drain).
// T2: LDS slot ^= (row&3) (64B rows -> 8-way conflict without it); write side stays
// linear (glds16 requirement) with inverse-swizzled GLOBAL source (rule #21).
// T5: setprio(1) around each 16-MFMA cluster. T1: bijective XCD swizzle (grids %8==0).
// RESID: 0=none. 3=split-K over gridDim.z, unsafeAtomicAdd into pre-primed fp32 Cout,
// bias only at z==0. ACT: 1=gelu. OUTF32: fp32 vs bf16 store (RESID==3 forces atomic).
template<int ACT, int RESID, int OUTF32>
__global__ __launch_bounds__(512, 2) void gemm_8p(
    const bf16* __restrict__ A, const bf16* __restrict__ Bw,
    const float* __restrict__ bias,
    void* __restrict__ Cout, int N, int K)
{
    __shared__ __align__(16) bf16 ring[4][16384];   // [slot]: A @0, B @8192 (128 KiB)
    const int t512 = threadIdx.x;
    const int lane = t512 & 63, w = t512 >> 6;
    const int quad = lane >> 4, l16 = lane & 15;
    const int wm = (w >> 2) * 128;          // 2 wave-rows of 128
    const int wn = (w & 3) * 64;            // 4 wave-cols of 64

    // T1: bijective XCD swizzle over linearized xy grid (nb % 8 == 0 for all uses)
    const int nb  = gridDim.x * gridDim.y;
    const int bid = blockIdx.y * gridDim.x + blockIdx.x;
    const int cpx = nb >> 3;
    const int swz = (bid & 7) * cpx + (bid >> 3);
    const int m0 = (swz / gridDim.x) * 256;
    const int n0 = (swz % gridDim.x) * 256;

    int k_lo = 0, k_hi = K;
    if (RESID == 3) { const int ks = K / gridDim.z; k_lo = blockIdx.z * ks; k_hi = k_lo + ks; }
    const int NK = (k_hi - k_lo) >> 5;

    // stage: 512 lanes, 4 lanes/row (16B each), 128 rows/round, 2 rounds = 256x32 tile.
    // LDS write is linear (lane*16); global col-group q = (lane&3) ^ (row&3) inverts T2.
    const int srow = t512 >> 2;             // 0..127
    auto stageA = [&](int u) {
        const int k0 = k_lo + (u << 5);
        const bf16* dst = ring[u & 3] + w * 512;
#pragma unroll
        for (int ra = 0; ra < 2; ra++) {
            const int row = ra * 128 + srow;
            const int q = (t512 & 3) ^ (row & 3);
            glds16(A + (size_t)(m0 + row) * K + k0 + q * 8, dst + ra * 4096);
        }
    };
    auto stageB = [&](int u) {
        const int k0 = k_lo + (u << 5);
        const bf16* dst = ring[u & 3] + 8192 + w * 512;
#pragma unroll
        for (int ra = 0; ra < 2; ra++) {
            const int row = ra * 128 + srow;
            const int q = (t512 & 3) ^ (row & 3);
            glds16(Bw + (size_t)(n0 + row) * K + k0 + q * 8, dst + ra * 4096);
        }
    };

    const f32x4 zero = {0.f, 0.f, 0.f, 0.f};
    f32x4 acc[8][4];
#pragma unroll
    for (int i = 0; i < 8; i++)
#pragma unroll
        for (int j = 0; j < 4; j++) acc[i][j] = zero;

    // prologue: stage tiles 0..2 (12 glds16/thread in flight)
    for (int u = 0; u < 3 && u < NK; ++u) { stageA(u); stageB(u); }

    const int aswz = (l16 & 3);   // read-side T2 swizzle source (row&3 == l16&3)
    for (int t = 0; t < NK; ++t) {
        // counted vmcnt: 8 loads (tiles t+1,t+2) issued since tile t's stage
        if (t < NK - 2)       asm volatile("s_waitcnt vmcnt(8)" ::: "memory");
        else if (t == NK - 2) asm volatile("s_waitcnt vmcnt(4)" ::: "memory");
        else                  asm volatile("s_waitcnt vmcnt(0)" ::: "memory");
        __builtin_amdgcn_s_barrier();       // all waves' tile-t loads landed
        const bf16* Ab = ring[t & 3];
        const bf16* Bb = Ab + 8192;
        bf16x8 af[4], bfr[4];
        // ---- phase 0: mi 0-3 x nj 0-3 ----
#pragma unroll
        for (int i = 0; i < 4; i++) {
            const int row = wm + i * 16 + l16;
            af[i] = *(const bf16x8*)(Ab + row * 32 + ((quad ^ aswz) * 8));
        }
#pragma unroll
        for (int j = 0; j < 4; j++) {
            const int row = wn + j * 16 + l16;
            bfr[j] = *(const bf16x8*)(Bb + row * 32 + ((quad ^ aswz) * 8));
        }
        if (t + 3 < NK) stageA(t + 3);
        asm volatile("s_waitcnt lgkmcnt(0)" ::: "memory");
        __builtin_amdgcn_sched_barrier(0);
        __builtin_amdgcn_s_setprio(1);
#pragma unroll
        for (int i = 0; i < 4; i++)
#pragma unroll
            for (int j = 0; j < 4; j++)
                acc[i][j] = __builtin_amdgcn_mfma_f32_16x16x32_bf16(af[i], bfr[j], acc[i][j], 0, 0, 0);
        __builtin_amdgcn_s_setprio(0);
        // ---- phase 1: mi 4-7 x nj 0-3 (B-frags reused) ----
        __builtin_amdgcn_s_barrier();
#pragma unroll
        for (int i = 0; i < 4; i++) {
            const int row = wm + 64 + i * 16 + l16;
            af[i] = *(const bf16x8*)(Ab + row * 32 + ((quad ^ aswz) * 8));
        }
        if (t + 3 < NK) stageB(t + 3);
        asm volatile("s_waitcnt lgkmcnt(0)" ::: "memory");
        __builtin_amdgcn_sched_barrier(0);
        __builtin_amdgcn_s_setprio(1);
#pragma unroll
        for (int i = 0; i < 4; i++)
#pragma unroll
            for (int j = 0; j < 4; j++)
                acc[4 + i][j] = __builtin_amdgcn_mfma_f32_16x16x32_bf16(af[i], bfr[j], acc[4 + i][j], 0, 0, 0);
        __builtin_amdgcn_s_setprio(0);
    }

    // ---- epilogue ----
#pragma unroll
    for (int i = 0; i < 8; i++) {
#pragma unroll
        for (int j = 0; j < 4; j++) {
            const int col = n0 + wn + j * 16 + l16;
            float bv = bias[col];
            if (RESID == 3 && blockIdx.z != 0) bv = 0.0f;
#pragma unroll
            for (int r = 0; r < 4; r++) {
                const int row = m0 + wm + i * 16 + quad * 4 + r;
                float val = acc[i][j][r] + bv;
                if (ACT == 1) val = gelu_f(val);
                size_t idx = (size_t)row * N + col;
                if (RESID == 3) {
                    unsafeAtomicAdd(&((float*)Cout)[idx], val);
                } else if (OUTF32) {
                    ((float*)Cout)[idx] = val;
                } else {
                    ((bf16*)Cout)[idx] = (bf16)val;
                }
            }
        }
    }
}

// ---------------- bf16 MFMA GEMM, 2-phase dbuf (kept for out-proj, N=1024) ----------
template<int TM, int ACT, int RESID, int OUTF32>
__global__ __launch_bounds__(256) void gemm_glds(
    const bf16* __restrict__ A, const bf16* __restrict__ Bw,
    const float* __restrict__ bias,
    const float* resid, void* __restrict__ Cout, int N, int K)
{
    constexpr int MI = 4;
    constexpr int NJ = (TM == 128) ? 4 : 2;
    __shared__ __align__(16) bf16 As[2 * TM * 32];
    __shared__ __align__(16) bf16 Bs[2 * 128 * 32];
    const int t = threadIdx.x;
    const int m0 = blockIdx.y * TM, n0 = blockIdx.x * 128;
    const int lane = t & 63, w = t >> 6;
    const int wm = (TM == 128) ? (w & 1) * 64 : 0;
    const int wn = (TM == 128) ? (w >> 1) * 64 : w * 32;
    const int quad = lane >> 4, l16 = lane & 15;
    const int srow = t >> 2, scol = (t & 3) * 8;

    const bf16* Ag = A  + (size_t)(m0 + srow) * K + scol;
    const bf16* Bg = Bw + (size_t)(n0 + srow) * K + scol;

    auto stage = [&](int buf, int k0) {
        const bf16* AsW = As + buf * (TM * 32) + w * 512;
        const bf16* BsW = Bs + buf * (128 * 32) + w * 512;
        glds16(Ag + k0, AsW);
        if (TM == 128) glds16(Ag + (size_t)64 * K + k0, AsW + 2048);
        glds16(Bg + k0, BsW);
        glds16(Bg + (size_t)64 * K + k0, BsW + 2048);
    };

    const f32x4 zero = {0.f, 0.f, 0.f, 0.f};
    f32x4 acc[MI][NJ];
#pragma unroll
    for (int i = 0; i < MI; i++)
#pragma unroll
        for (int j = 0; j < NJ; j++) acc[i][j] = zero;

    const int nsteps = K >> 5;
    stage(0, 0);
    __syncthreads();

    for (int step = 0; step < nsteps; ++step) {
        const int cur = step & 1;
        if (step + 1 < nsteps)
            stage(cur ^ 1, (step + 1) << 5);
        const bf16* Ab = As + cur * (TM * 32);
        const bf16* Bb = Bs + cur * (128 * 32);
        bf16x8 af[MI], bfr[NJ];
#pragma unroll
        for (int i = 0; i < MI; i++)
            af[i] = *(const bf16x8*)(Ab + (wm + i * 16 + l16) * 32 + quad * 8);
#pragma unroll
        for (int j = 0; j < NJ; j++)
            bfr[j] = *(const bf16x8*)(Bb + (wn + j * 16 + l16) * 32 + quad * 8);
#pragma unroll
        for (int i = 0; i < MI; i++)
#pragma unroll
            for (int j = 0; j < NJ; j++)
                acc[i][j] = __builtin_amdgcn_mfma_f32_16x16x32_bf16(af[i], bfr[j], acc[i][j], 0, 0, 0);
        __syncthreads();
    }

#pragma unroll
    for (int i = 0; i < MI; i++) {
#pragma unroll
        for (int j = 0; j < NJ; j++) {
            int col = n0 + wn + j * 16 + l16;
            float bv = bias[col];
#pragma unroll
            for (int r = 0; r < 4; r++) {
                int row = m0 + wm + i * 16 + quad * 4 + r;
                float val = acc[i][j][r] + bv;
                if (ACT == 1) val = gelu_f(val);
                size_t idx = (size_t)row * N + col;
                if (RESID == 2) val += resid[idx];
                if (OUTF32) ((float*)Cout)[idx] = val;
                else        ((bf16*)Cout)[idx] = (bf16)val;
            }
        }
    }
}

// ---------------- Sliding-window causal attention, MFMA-tiled ----------------
__global__ __launch_bounds__(256) void attn_kernel(
    const bf16* __restrict__ qkv, bf16* __restrict__ o)
{
    __shared__ __align__(16) bf16 Vlds[4][32 * 64];
    __shared__ __align__(16) bf16 Plds[4][16 * 32];
    const int t = threadIdx.x;
    const int w = t >> 6, lane = t & 63;
    const int quad = lane >> 4, l16 = lane & 15;
    const int gw = blockIdx.x * 4 + w;
    const int qb = gw & 127;
    const int h  = (gw >> 7) & (HH - 1);
    const int b  = gw >> 11;
    const int q0 = qb << 4;
    const size_t rs = 3 * DD;
    const bf16* Qb = qkv + (size_t)b * SS * rs + h * HDD;
    const bf16* Kb = Qb + DD;
    const bf16* Vb = Qb + 2 * DD;
    bf16* Vw = Vlds[w];
    bf16* Pw = Plds[w];

    {
        const int sub = lane >> 3;
        const int dc  = (lane & 7) * 8;
#pragma unroll
        for (int c = 0; c < 4; c++) {
            int key = q0 - 16 + c * 8 + sub;
            if (key < 0) key = 0;
            glds16(Vb + (size_t)key * rs + dc, Vw + c * 512);
        }
    }

    const int qrow = q0 + l16;
    int kr0 = q0 - 16 + l16; if (kr0 < 0) kr0 = 0;
    bf16x8 qf0  = *(const bf16x8*)(Qb + (size_t)qrow * rs + quad * 8);
    bf16x8 qf1  = *(const bf16x8*)(Qb + (size_t)qrow * rs + 32 + quad * 8);
    bf16x8 kf0a = *(const bf16x8*)(Kb + (size_t)kr0  * rs + quad * 8);
    bf16x8 kf0b = *(const bf16x8*)(Kb + (size_t)kr0  * rs + 32 + quad * 8);
    bf16x8 kf1a = *(const bf16x8*)(Kb + (size_t)qrow * rs + quad * 8);
    bf16x8 kf1b = *(const bf16x8*)(Kb + (size_t)qrow * rs + 32 + quad * 8);

    const f32x4 zero = {0.f, 0.f, 0.f, 0.f};
    f32x4 acc0 = __builtin_amdgcn_mfma_f32_16x16x32_bf16(qf0, kf0a, zero, 0, 0, 0);
    acc0 = __builtin_amdgcn_mfma_f32_16x16x32_bf16(qf1, kf0b, acc0, 0, 0, 0);
    f32x4 acc1 = __builtin_amdgcn_mfma_f32_16x16x32_bf16(qf0, kf1a, zero, 0, 0, 0);
    acc1 = __builtin_amdgcn_mfma_f32_16x16x32_bf16(qf1, kf1b, acc1, 0, 0, 0);

    float rl[4];
#pragma unroll
    for (int r = 0; r < 4; r++) {
        const int row = quad * 4 + r;
        float s0 = (l16 > row && q0 - 16 + l16 >= 0) ? acc0[r] * 0.125f : -1e30f;
        float s1 = (l16 <= row)                      ? acc1[r] * 0.125f : -1e30f;
        float m = fmaxf(s0, s1);
        m = fmaxf(m, __shfl_xor(m, 1, 64));
        m = fmaxf(m, __shfl_xor(m, 2, 64));
        m = fmaxf(m, __shfl_xor(m, 4, 64));
        m = fmaxf(m, __shfl_xor(m, 8, 64));
        float e0 = __expf(s0 - m), e1 = __expf(s1 - m);
        float sum = e0 + e1;
        sum += __shfl_xor(sum, 1, 64);
        sum += __shfl_xor(sum, 2, 64);
        sum += __shfl_xor(sum, 4, 64);
        sum += __shfl_xor(sum, 8, 64);
        rl[r] = 1.0f / sum;
        Pw[row * 32 + l16]      = (bf16)e0;
        Pw[row * 32 + 16 + l16] = (bf16)e1;
    }

    asm volatile("s_waitcnt vmcnt(0)" ::: "memory");
    bf16x8 pf = *(const bf16x8*)(Pw + l16 * 32 + quad * 8);
#pragma unroll
    for (int dt = 0; dt < 4; dt++) {
        bf16x8 vf;
#pragma unroll
        for (int jj = 0; jj < 8; jj++)
            vf[jj] = Vw[(quad * 8 + jj) * 64 + dt * 16 + l16];
        f32x4 ov = __builtin_amdgcn_mfma_f32_16x16x32_bf16(pf, vf, zero, 0, 0, 0);
#pragma unroll
        for (int r = 0; r < 4; r++) {
            const int row = quad * 4 + r;
            o[(size_t)(b * SS + q0 + row) * DD + h * HDD + dt * 16 + l16] =
                (bf16)(ov[r] * rl[r]);
        }
    }
}

// ---------------- launch ----------------
extern "C" void kernel_launch(void* const* d_in, const int* in_sizes, int n_in,
                              void* d_out, int out_size, void* d_ws, size_t ws_size,
                              hipStream_t stream)
{
    (void)in_sizes; (void)n_in; (void)out_size; (void)ws_size;
    const float* x    = (const float*)d_in[0];
    const float* ln1g = (const float*)d_in[1];
    const float* ln1b = (const float*)d_in[2];
    const float* Wqkv = (const float*)d_in[3];
    const float* bqkv = (const float*)d_in[4];
    const float* Wout = (const float*)d_in[5];
    const float* bout = (const float*)d_in[6];
    const float* ln2g = (const float*)d_in[7];
    const float* ln2b = (const float*)d_in[8];
    const float* W1   = (const float*)d_in[9];
    const float* b1   = (const float*)d_in[10];
    const float* W2   = (const float*)d_in[11];
    const float* b2   = (const float*)d_in[12];

    // Workspace (56 MiB peak):
    //   [0,16M)  W region. Phase A: Wqkv_bf @0..6M, Wout_bf @6..8M.
    //            Phase B: W1_bf @0..8M, W2_bf @8..16M (conv after out-proj).
    //   [16,48M) P region. Phase A: qkv bf16 24 MiB. Phase B: h1 bf16 32 MiB.
    //   [48,56M) H region: h (LN1 out) -> o (attn out) -> xn (LN2 out), serially.
    //   x1 fp32 lives in d_out; MLP2 split-K atomically accumulates in place.
    const size_t MB = (size_t)1 << 20;
    char* ws = (char*)d_ws;
    bf16* wqkv_bf = (bf16*)(ws);
    bf16* wout_bf = (bf16*)(ws + 6 * MB);
    bf16* w1_bf   = (bf16*)(ws);
    bf16* w2_bf   = (bf16*)(ws + 8 * MB);
    bf16* qkv     = (bf16*)(ws + 16 * MB);
    bf16* h1      = (bf16*)(ws + 16 * MB);
    bf16* hbuf    = (bf16*)(ws + 48 * MB);   // h, then o, then xn
    float* x1     = (float*)d_out;

    const dim3 blk(256);
    const dim3 blk512(512);

    // Phase A: weights for QKV + out-proj
    conv_kernel<<<(3 * DD * DD / 8) / 256, blk, 0, stream>>>(Wqkv, wqkv_bf, 3 * DD * DD / 8);
    conv_kernel<<<(DD * DD / 8) / 256, blk, 0, stream>>>(Wout, wout_bf, DD * DD / 8);
    // h = LN1(x)
    ln_kernel<<<NTOK, blk, 0, stream>>>(x, ln1g, ln1b, hbuf);
    // qkv = h @ Wqkv^T + bqkv           (M=4096, N=3072, K=1024; 12x16=192 blocks)
    gemm_8p<0, 0, 0><<<dim3(12, 16), blk512, 0, stream>>>(
        hbuf, wqkv_bf, bqkv, qkv, 3 * DD, DD);
    // o = attention(qkv)  (o overwrites h — h dead)
    attn_kernel<<<BB * HH * (SS / 16) / 4, blk, 0, stream>>>(qkv, hbuf);
    // x1 = x + o @ Wout^T + bout        (fp32 into d_out; M=4096, N=1024, K=1024)
    gemm_glds<64, 0, 2, 1><<<dim3(8, 64), blk, 0, stream>>>(
        hbuf, wout_bf, bout, x, x1, DD, DD);

    // Phase B: weights for MLP
    conv_kernel<<<(DFFD * DD / 8) / 256, blk, 0, stream>>>(W1, w1_bf, DFFD * DD / 8);
    conv_kernel<<<(DFFD * DD / 8) / 256, blk, 0, stream>>>(W2, w2_bf, DFFD * DD / 8);
    // xn = LN2(x1)   (xn overwrites o — o dead)
    ln_kernel<<<NTOK, blk, 0, stream>>>(x1, ln2g, ln2b, hbuf);
    // h1 = gelu(xn @ W1^T + b1)         (M=4096, N=4096, K=1024; 16x16=256 blocks)
    gemm_8p<1, 0, 0><<<dim3(16, 16), blk512, 0, stream>>>(
        hbuf, w1_bf, b1, h1, DFFD, DD);
    // out = x1 + h1 @ W2^T + b2         (split-K=4: 4x16x4=256 blocks, slice K=1024;
    //   atomics into pre-primed x1 in d_out)
    gemm_8p<0, 3, 1><<<dim3(4, 16, 4), blk512, 0, stream>>>(
        h1, w2_bf, b2, x1, DD, DFFD);
}

// Round 5
// 305.412 us; speedup vs baseline: 1.0412x; 1.0412x over previous
//
#include <hip/hip_runtime.h>
#include <hip/hip_bf16.h>
#include <cmath>

typedef __bf16 bf16;
typedef __bf16 bf16x4 __attribute__((ext_vector_type(4)));
typedef __bf16 bf16x8 __attribute__((ext_vector_type(8)));
typedef float f32x4 __attribute__((ext_vector_type(4)));

#define BB 2
#define SS 2048
#define DD 1024
#define HH 16
#define WW 16
#define HDD 64
#define DFFD 4096
#define NTOK (BB*SS)

// gelu(x) = x * sigmoid(2*sqrt(2/pi)*(x+0.044715x^3))  == tanh-approx gelu
__device__ __forceinline__ float gelu_f(float x) {
    const float k = 1.5957691216057308f;  // 2*sqrt(2/pi)
    float u = k * (x + 0.044715f * x * x * x);
    return x / (1.0f + __expf(-u));
}

// ---- async global->LDS 16B/lane. LDS dest = wave-uniform base; HW adds lane*16. ----
__device__ __forceinline__ void glds16(const bf16* g, const bf16* l) {
    __builtin_amdgcn_global_load_lds(
        (const __attribute__((address_space(1))) void*)(uintptr_t)(const void*)g,
        (__attribute__((address_space(3))) void*)(unsigned)(uintptr_t)(const void*)l,
        16, 0, 0);
}

// ---------------- fp32 -> bf16 convert, 8 elems/thread ----------------
__global__ __launch_bounds__(256) void conv_kernel(
    const float* __restrict__ src, bf16* __restrict__ dst, int n8)
{
    int i = blockIdx.x * 256 + threadIdx.x;
    if (i >= n8) return;
    f32x4 a = *(const f32x4*)(src + (size_t)i * 8);
    f32x4 b = *(const f32x4*)(src + (size_t)i * 8 + 4);
    bf16x8 v;
#pragma unroll
    for (int j = 0; j < 4; j++) { v[j] = (bf16)a[j]; v[4 + j] = (bf16)b[j]; }
    *(bf16x8*)(dst + (size_t)i * 8) = v;
}

// ---------------- fused LayerNorm: fp32 row -> bf16 row, one block/row ----------------
__global__ __launch_bounds__(256) void ln_kernel(
    const float* __restrict__ x, const float* __restrict__ g, const float* __restrict__ b,
    bf16* __restrict__ out)
{
    const int row = blockIdx.x, t = threadIdx.x;
    f32x4 v = *(const f32x4*)(x + (size_t)row * DD + t * 4);
    float s  = v[0] + v[1] + v[2] + v[3];
    float s2 = v[0]*v[0] + v[1]*v[1] + v[2]*v[2] + v[3]*v[3];
#pragma unroll
    for (int off = 32; off >= 1; off >>= 1) {
        s  += __shfl_xor(s,  off, 64);
        s2 += __shfl_xor(s2, off, 64);
    }
    __shared__ float red[8];
    const int wave = t >> 6;
    if ((t & 63) == 0) { red[wave] = s; red[4 + wave] = s2; }
    __syncthreads();
    float ts  = red[0] + red[1] + red[2] + red[3];
    float ts2 = red[4] + red[5] + red[6] + red[7];
    float mean = ts * (1.0f / DD);
    float var  = ts2 * (1.0f / DD) - mean * mean;
    float rstd = rsqrtf(var + 1e-5f);
    f32x4 gv = *(const f32x4*)(g + t * 4);
    f32x4 bv = *(const f32x4*)(b + t * 4);
    bf16x4 o;
#pragma unroll
    for (int i = 0; i < 4; i++) o[i] = (bf16)((v[i] - mean) * rstd * gv[i] + bv[i]);
    *(bf16x4*)(out + (size_t)row * DD + t * 4) = o;
}

// ======== 256x256 8-wave phase-pipelined GEMM (T1+T2+T3+T4+T5), BK=32 ring-4 ========
// C[M,N] = A[M,K] @ W[N,K]^T + bias.  512 threads = 8 waves (2M x 4N), wave tile 128x64.
// LDS: ring of 4 K-tile slots (A 256x32 + B 256x32 = 32 KB each) = 128 KiB.
// Schedule: iter t computes tile t from ring[t&3], stages tile t+3 (A in phase 0,
// B in phase 1). Counted vmcnt(8) before the phase-0 barrier: exactly 8 loads
// (tiles t+1,t+2) were issued after tile t's stage. Tail drains 8->4->0.
// Raw s_barrier only (no __syncthreads -> no vmcnt(0) drain).
// T2 (fixed R4): bank = (row*16 + slot*4 + dw)%32, so only row&1 and slot reach the
// bank bits. slot = quad ^ ((row>>1)&3) gives each 16-lane group all 8
// (slot,parity) bank-groups exactly twice -> 2-way = free (m136). Write side linear
// (glds16 requirement) with inverse-permuted GLOBAL source (rule #21): the XOR is
// its own inverse, and (row'>>1)&3 == (l16>>1)&3 for all fragment rows (bases =0 mod 8).
// T5: setprio(1) around each 16-MFMA cluster. T1: bijective XCD swizzle (grids %8==0).
template<int ACT>
__global__ __launch_bounds__(512, 2) void gemm_8p(
    const bf16* __restrict__ A, const bf16* __restrict__ Bw,
    const float* __restrict__ bias,
    void* __restrict__ Cout, int N, int K)
{
    __shared__ __align__(16) bf16 ring[4][16384];   // [slot]: A @0, B @8192 (128 KiB)
    const int t512 = threadIdx.x;
    const int lane = t512 & 63, w = t512 >> 6;
    const int quad = lane >> 4, l16 = lane & 15;
    const int wm = (w >> 2) * 128;          // 2 wave-rows of 128
    const int wn = (w & 3) * 64;            // 4 wave-cols of 64

    // T1: bijective XCD swizzle over linearized xy grid (nb % 8 == 0 for all uses)
    const int nb  = gridDim.x * gridDim.y;
    const int bid = blockIdx.y * gridDim.x + blockIdx.x;
    const int cpx = nb >> 3;
    const int swz = (bid & 7) * cpx + (bid >> 3);
    const int m0 = (swz / gridDim.x) * 256;
    const int n0 = (swz % gridDim.x) * 256;

    const int NK = K >> 5;

    // stage: 512 lanes, 4 lanes/row (16B each), 128 rows/round, 2 rounds = 256x32 tile.
    // LDS write linear (lane*16); global col-group q = (t&3) ^ ((srow>>1)&3) (T2 inverse).
    const int srow = t512 >> 2;             // 0..127
    const int qsw  = (t512 & 3) ^ ((srow >> 1) & 3);
    auto stageA = [&](int u) {
        const int k0 = (u << 5);
        const bf16* dst = ring[u & 3] + w * 512;
#pragma unroll
        for (int ra = 0; ra < 2; ra++) {
            const int row = ra * 128 + srow;
            glds16(A + (size_t)(m0 + row) * K + k0 + qsw * 8, dst + ra * 4096);
        }
    };
    auto stageB = [&](int u) {
        const int k0 = (u << 5);
        const bf16* dst = ring[u & 3] + 8192 + w * 512;
#pragma unroll
        for (int ra = 0; ra < 2; ra++) {
            const int row = ra * 128 + srow;
            glds16(Bw + (size_t)(n0 + row) * K + k0 + qsw * 8, dst + ra * 4096);
        }
    };

    const f32x4 zero = {0.f, 0.f, 0.f, 0.f};
    f32x4 acc[8][4];
#pragma unroll
    for (int i = 0; i < 8; i++)
#pragma unroll
        for (int j = 0; j < 4; j++) acc[i][j] = zero;

    // prologue: stage tiles 0..2 (12 glds16/thread in flight)
    for (int u = 0; u < 3 && u < NK; ++u) { stageA(u); stageB(u); }

    const int rsl = (quad ^ ((l16 >> 1) & 3)) * 8;   // read-side T2 slot (bf16 offset)
    for (int t = 0; t < NK; ++t) {
        // counted vmcnt: 8 loads (tiles t+1,t+2) issued since tile t's stage
        if (t < NK - 2)       asm volatile("s_waitcnt vmcnt(8)" ::: "memory");
        else if (t == NK - 2) asm volatile("s_waitcnt vmcnt(4)" ::: "memory");
        else                  asm volatile("s_waitcnt vmcnt(0)" ::: "memory");
        __builtin_amdgcn_s_barrier();       // all waves' tile-t loads landed
        const bf16* Ab = ring[t & 3];
        const bf16* Bb = Ab + 8192;
        bf16x8 af[4], bfr[4];
        // ---- phase 0: mi 0-3 x nj 0-3 ----
#pragma unroll
        for (int i = 0; i < 4; i++)
            af[i] = *(const bf16x8*)(Ab + (wm + i * 16 + l16) * 32 + rsl);
#pragma unroll
        for (int j = 0; j < 4; j++)
            bfr[j] = *(const bf16x8*)(Bb + (wn + j * 16 + l16) * 32 + rsl);
        if (t + 3 < NK) stageA(t + 3);
        asm volatile("s_waitcnt lgkmcnt(0)" ::: "memory");
        __builtin_amdgcn_sched_barrier(0);
        __builtin_amdgcn_s_setprio(1);
#pragma unroll
        for (int i = 0; i < 4; i++)
#pragma unroll
            for (int j = 0; j < 4; j++)
                acc[i][j] = __builtin_amdgcn_mfma_f32_16x16x32_bf16(af[i], bfr[j], acc[i][j], 0, 0, 0);
        __builtin_amdgcn_s_setprio(0);
        // ---- phase 1: mi 4-7 x nj 0-3 (B-frags reused) ----
        __builtin_amdgcn_s_barrier();
#pragma unroll
        for (int i = 0; i < 4; i++)
            af[i] = *(const bf16x8*)(Ab + (wm + 64 + i * 16 + l16) * 32 + rsl);
        if (t + 3 < NK) stageB(t + 3);
        asm volatile("s_waitcnt lgkmcnt(0)" ::: "memory");
        __builtin_amdgcn_sched_barrier(0);
        __builtin_amdgcn_s_setprio(1);
#pragma unroll
        for (int i = 0; i < 4; i++)
#pragma unroll
            for (int j = 0; j < 4; j++)
                acc[4 + i][j] = __builtin_amdgcn_mfma_f32_16x16x32_bf16(af[i], bfr[j], acc[4 + i][j], 0, 0, 0);
        __builtin_amdgcn_s_setprio(0);
    }

    // ---- epilogue ----
#pragma unroll
    for (int i = 0; i < 8; i++) {
#pragma unroll
        for (int j = 0; j < 4; j++) {
            const int col = n0 + wn + j * 16 + l16;
            float bv = bias[col];
#pragma unroll
            for (int r = 0; r < 4; r++) {
                const int row = m0 + wm + i * 16 + quad * 4 + r;
                float val = acc[i][j][r] + bv;
                if (ACT == 1) val = gelu_f(val);
                ((bf16*)Cout)[(size_t)row * N + col] = (bf16)val;
            }
        }
    }
}

// ---------------- bf16 MFMA GEMM, 2-phase dbuf (out-proj, MLP2) ----------------
// TM=128 (waves 2x2, 4x4) or 64 (1x4, 4x2). RESID: 2=add fp32 resid (may alias Cout,
// same elem same thread). 3=split-K over gridDim.z, unsafeAtomicAdd into pre-primed
// fp32 Cout, bias at z==0 only. OUTF32: 1=fp32, 0=bf16.
template<int TM, int ACT, int RESID, int OUTF32>
__global__ __launch_bounds__(256) void gemm_glds(
    const bf16* __restrict__ A, const bf16* __restrict__ Bw,
    const float* __restrict__ bias,
    const float* resid, void* __restrict__ Cout, int N, int K)
{
    constexpr int MI = 4;
    constexpr int NJ = (TM == 128) ? 4 : 2;
    __shared__ __align__(16) bf16 As[2 * TM * 32];
    __shared__ __align__(16) bf16 Bs[2 * 128 * 32];
    const int t = threadIdx.x;
    const int m0 = blockIdx.y * TM, n0 = blockIdx.x * 128;
    const int lane = t & 63, w = t >> 6;
    const int wm = (TM == 128) ? (w & 1) * 64 : 0;
    const int wn = (TM == 128) ? (w >> 1) * 64 : w * 32;
    const int quad = lane >> 4, l16 = lane & 15;
    const int srow = t >> 2, scol = (t & 3) * 8;

    const bf16* Ag = A  + (size_t)(m0 + srow) * K + scol;
    const bf16* Bg = Bw + (size_t)(n0 + srow) * K + scol;

    int k_lo = 0, k_hi = K;
    if (RESID == 3) {                 // split-K: this block handles one K-slice
        const int ks = K / gridDim.z;
        k_lo = blockIdx.z * ks;
        k_hi = k_lo + ks;
    }

    auto stage = [&](int buf, int k0) {
        const bf16* AsW = As + buf * (TM * 32) + w * 512;
        const bf16* BsW = Bs + buf * (128 * 32) + w * 512;
        glds16(Ag + k0, AsW);
        if (TM == 128) glds16(Ag + (size_t)64 * K + k0, AsW + 2048);
        glds16(Bg + k0, BsW);
        glds16(Bg + (size_t)64 * K + k0, BsW + 2048);
    };

    const f32x4 zero = {0.f, 0.f, 0.f, 0.f};
    f32x4 acc[MI][NJ];
#pragma unroll
    for (int i = 0; i < MI; i++)
#pragma unroll
        for (int j = 0; j < NJ; j++) acc[i][j] = zero;

    const int nsteps = (k_hi - k_lo) >> 5;
    stage(0, k_lo);
    __syncthreads();

    for (int step = 0; step < nsteps; ++step) {
        const int cur = step & 1;
        if (step + 1 < nsteps)
            stage(cur ^ 1, k_lo + ((step + 1) << 5));
        const bf16* Ab = As + cur * (TM * 32);
        const bf16* Bb = Bs + cur * (128 * 32);
        bf16x8 af[MI], bfr[NJ];
#pragma unroll
        for (int i = 0; i < MI; i++)
            af[i] = *(const bf16x8*)(Ab + (wm + i * 16 + l16) * 32 + quad * 8);
#pragma unroll
        for (int j = 0; j < NJ; j++)
            bfr[j] = *(const bf16x8*)(Bb + (wn + j * 16 + l16) * 32 + quad * 8);
#pragma unroll
        for (int i = 0; i < MI; i++)
#pragma unroll
            for (int j = 0; j < NJ; j++)
                acc[i][j] = __builtin_amdgcn_mfma_f32_16x16x32_bf16(af[i], bfr[j], acc[i][j], 0, 0, 0);
        __syncthreads();
    }

#pragma unroll
    for (int i = 0; i < MI; i++) {
#pragma unroll
        for (int j = 0; j < NJ; j++) {
            int col = n0 + wn + j * 16 + l16;
            float bv = bias[col];
            if (RESID == 3 && blockIdx.z != 0) bv = 0.0f;
#pragma unroll
            for (int r = 0; r < 4; r++) {
                int row = m0 + wm + i * 16 + quad * 4 + r;
                float val = acc[i][j][r] + bv;
                if (ACT == 1) val = gelu_f(val);
                size_t idx = (size_t)row * N + col;
                if (RESID == 2) val += resid[idx];
                if (RESID == 3) {
                    unsafeAtomicAdd(&((float*)Cout)[idx], val);   // HW global_atomic_add_f32
                } else if (OUTF32) {
                    ((float*)Cout)[idx] = val;
                } else {
                    ((bf16*)Cout)[idx] = (bf16)val;
                }
            }
        }
    }
}

// ---------------- Sliding-window causal attention, MFMA-tiled ----------------
__global__ __launch_bounds__(256) void attn_kernel(
    const bf16* __restrict__ qkv, bf16* __restrict__ o)
{
    __shared__ __align__(16) bf16 Vlds[4][32 * 64];
    __shared__ __align__(16) bf16 Plds[4][16 * 32];
    const int t = threadIdx.x;
    const int w = t >> 6, lane = t & 63;
    const int quad = lane >> 4, l16 = lane & 15;
    const int gw = blockIdx.x * 4 + w;
    const int qb = gw & 127;
    const int h  = (gw >> 7) & (HH - 1);
    const int b  = gw >> 11;
    const int q0 = qb << 4;
    const size_t rs = 3 * DD;
    const bf16* Qb = qkv + (size_t)b * SS * rs + h * HDD;
    const bf16* Kb = Qb + DD;
    const bf16* Vb = Qb + 2 * DD;
    bf16* Vw = Vlds[w];
    bf16* Pw = Plds[w];

    {
        const int sub = lane >> 3;
        const int dc  = (lane & 7) * 8;
#pragma unroll
        for (int c = 0; c < 4; c++) {
            int key = q0 - 16 + c * 8 + sub;
            if (key < 0) key = 0;
            glds16(Vb + (size_t)key * rs + dc, Vw + c * 512);
        }
    }

    const int qrow = q0 + l16;
    int kr0 = q0 - 16 + l16; if (kr0 < 0) kr0 = 0;
    bf16x8 qf0  = *(const bf16x8*)(Qb + (size_t)qrow * rs + quad * 8);
    bf16x8 qf1  = *(const bf16x8*)(Qb + (size_t)qrow * rs + 32 + quad * 8);
    bf16x8 kf0a = *(const bf16x8*)(Kb + (size_t)kr0  * rs + quad * 8);
    bf16x8 kf0b = *(const bf16x8*)(Kb + (size_t)kr0  * rs + 32 + quad * 8);
    bf16x8 kf1a = *(const bf16x8*)(Kb + (size_t)qrow * rs + quad * 8);
    bf16x8 kf1b = *(const bf16x8*)(Kb + (size_t)qrow * rs + 32 + quad * 8);

    const f32x4 zero = {0.f, 0.f, 0.f, 0.f};
    f32x4 acc0 = __builtin_amdgcn_mfma_f32_16x16x32_bf16(qf0, kf0a, zero, 0, 0, 0);
    acc0 = __builtin_amdgcn_mfma_f32_16x16x32_bf16(qf1, kf0b, acc0, 0, 0, 0);
    f32x4 acc1 = __builtin_amdgcn_mfma_f32_16x16x32_bf16(qf0, kf1a, zero, 0, 0, 0);
    acc1 = __builtin_amdgcn_mfma_f32_16x16x32_bf16(qf1, kf1b, acc1, 0, 0, 0);

    float rl[4];
#pragma unroll
    for (int r = 0; r < 4; r++) {
        const int row = quad * 4 + r;
        float s0 = (l16 > row && q0 - 16 + l16 >= 0) ? acc0[r] * 0.125f : -1e30f;
        float s1 = (l16 <= row)                      ? acc1[r] * 0.125f : -1e30f;
        float m = fmaxf(s0, s1);
        m = fmaxf(m, __shfl_xor(m, 1, 64));
        m = fmaxf(m, __shfl_xor(m, 2, 64));
        m = fmaxf(m, __shfl_xor(m, 4, 64));
        m = fmaxf(m, __shfl_xor(m, 8, 64));
        float e0 = __expf(s0 - m), e1 = __expf(s1 - m);
        float sum = e0 + e1;
        sum += __shfl_xor(sum, 1, 64);
        sum += __shfl_xor(sum, 2, 64);
        sum += __shfl_xor(sum, 4, 64);
        sum += __shfl_xor(sum, 8, 64);
        rl[r] = 1.0f / sum;
        Pw[row * 32 + l16]      = (bf16)e0;
        Pw[row * 32 + 16 + l16] = (bf16)e1;
    }

    asm volatile("s_waitcnt vmcnt(0)" ::: "memory");
    bf16x8 pf = *(const bf16x8*)(Pw + l16 * 32 + quad * 8);
#pragma unroll
    for (int dt = 0; dt < 4; dt++) {
        bf16x8 vf;
#pragma unroll
        for (int jj = 0; jj < 8; jj++)
            vf[jj] = Vw[(quad * 8 + jj) * 64 + dt * 16 + l16];
        f32x4 ov = __builtin_amdgcn_mfma_f32_16x16x32_bf16(pf, vf, zero, 0, 0, 0);
#pragma unroll
        for (int r = 0; r < 4; r++) {
            const int row = quad * 4 + r;
            o[(size_t)(b * SS + q0 + row) * DD + h * HDD + dt * 16 + l16] =
                (bf16)(ov[r] * rl[r]);
        }
    }
}

// ---------------- launch ----------------
extern "C" void kernel_launch(void* const* d_in, const int* in_sizes, int n_in,
                              void* d_out, int out_size, void* d_ws, size_t ws_size,
                              hipStream_t stream)
{
    (void)in_sizes; (void)n_in; (void)out_size; (void)ws_size;
    const float* x    = (const float*)d_in[0];
    const float* ln1g = (const float*)d_in[1];
    const float* ln1b = (const float*)d_in[2];
    const float* Wqkv = (const float*)d_in[3];
    const float* bqkv = (const float*)d_in[4];
    const float* Wout = (const float*)d_in[5];
    const float* bout = (const float*)d_in[6];
    const float* ln2g = (const float*)d_in[7];
    const float* ln2b = (const float*)d_in[8];
    const float* W1   = (const float*)d_in[9];
    const float* b1   = (const float*)d_in[10];
    const float* W2   = (const float*)d_in[11];
    const float* b2   = (const float*)d_in[12];

    // Workspace (56 MiB peak):
    //   [0,16M)  W region. Phase A: Wqkv_bf @0..6M, Wout_bf @6..8M.
    //            Phase B: W1_bf @0..8M, W2_bf @8..16M (conv after out-proj).
    //   [16,48M) P region. Phase A: qkv bf16 24 MiB. Phase B: h1 bf16 32 MiB.
    //   [48,56M) H region: h (LN1 out) -> o (attn out) -> xn (LN2 out), serially.
    //   x1 fp32 lives in d_out; MLP2 split-K atomically accumulates in place.
    const size_t MB = (size_t)1 << 20;
    char* ws = (char*)d_ws;
    bf16* wqkv_bf = (bf16*)(ws);
    bf16* wout_bf = (bf16*)(ws + 6 * MB);
    bf16* w1_bf   = (bf16*)(ws);
    bf16* w2_bf   = (bf16*)(ws + 8 * MB);
    bf16* qkv     = (bf16*)(ws + 16 * MB);
    bf16* h1      = (bf16*)(ws + 16 * MB);
    bf16* hbuf    = (bf16*)(ws + 48 * MB);   // h, then o, then xn
    float* x1     = (float*)d_out;

    const dim3 blk(256);
    const dim3 blk512(512);

    // Phase A: weights for QKV + out-proj
    conv_kernel<<<(3 * DD * DD / 8) / 256, blk, 0, stream>>>(Wqkv, wqkv_bf, 3 * DD * DD / 8);
    conv_kernel<<<(DD * DD / 8) / 256, blk, 0, stream>>>(Wout, wout_bf, DD * DD / 8);
    // h = LN1(x)
    ln_kernel<<<NTOK, blk, 0, stream>>>(x, ln1g, ln1b, hbuf);
    // qkv = h @ Wqkv^T + bqkv           (M=4096, N=3072, K=1024; 12x16=192 blocks)
    gemm_8p<0><<<dim3(12, 16), blk512, 0, stream>>>(
        hbuf, wqkv_bf, bqkv, qkv, 3 * DD, DD);
    // o = attention(qkv)  (o overwrites h — h dead)
    attn_kernel<<<BB * HH * (SS / 16) / 4, blk, 0, stream>>>(qkv, hbuf);
    // x1 = x + o @ Wout^T + bout        (fp32 into d_out; M=4096, N=1024, K=1024)
    gemm_glds<64, 0, 2, 1><<<dim3(8, 64), blk, 0, stream>>>(
        hbuf, wout_bf, bout, x, x1, DD, DD);

    // Phase B: weights for MLP
    conv_kernel<<<(DFFD * DD / 8) / 256, blk, 0, stream>>>(W1, w1_bf, DFFD * DD / 8);
    conv_kernel<<<(DFFD * DD / 8) / 256, blk, 0, stream>>>(W2, w2_bf, DFFD * DD / 8);
    // xn = LN2(x1)   (xn overwrites o — o dead)
    ln_kernel<<<NTOK, blk, 0, stream>>>(x1, ln2g, ln2b, hbuf);
    // h1 = gelu(xn @ W1^T + b1)         (M=4096, N=4096, K=1024; 16x16=256 blocks)
    gemm_8p<1><<<dim3(16, 16), blk512, 0, stream>>>(
        hbuf, w1_bf, b1, h1, DFFD, DD);
    // out = x1 + h1 @ W2^T + b2         (proven R2 path: split-K=2, TM=128,
    //   512 blocks = 2/CU; 8.4M atomics into pre-primed x1 in d_out)
    gemm_glds<128, 0, 3, 1><<<dim3(8, 32, 2), blk, 0, stream>>>(
        h1, w2_bf, b2, nullptr, x1, DD, DFFD);
}